// Round 4
// baseline (208.077 us; speedup 1.0000x reference)
//
#include <hip/hip_runtime.h>
#include <math.h>

#define N_NODES 50000
#define E_EDGES 800000
#define IN_DIM 128
#define HEADS 4
#define OUT_DIM 32
#define HD 128          // HEADS*OUT_DIM
#define LEAKY 0.4f
#define BN_EPS 1e-5f

// bucketed counting sort params: bucket = tgt >> 7 (128 targets/bucket)
#define BSH 7
#define NB ((N_NODES + 127) >> BSH)     // 391
#define FB 196                           // kb_fill block count
#define FCH 4096                         // edges per kb_fill block
#define PCAP 2560                        // padded bucket capacity (mean 2048, sd 45)
#define SCCH ((NB + 63) / 64)            // 7: scan chunk per lane
#define K1B ((N_NODES + 63) / 64)        // 782 GEMM blocks
#define K2_BLOCKS 32
#define HSL (N_NODES * 32)               // ushorts per head slice of hb

typedef __attribute__((ext_vector_type(8))) short short8;
typedef __attribute__((ext_vector_type(8))) unsigned short us8;
typedef __attribute__((ext_vector_type(4))) float f32x4;

// ---- monotonic float<->uint encoding for atomicMax on floats ----
__device__ __forceinline__ unsigned enc_max(float f) {
    unsigned u = __float_as_uint(f);
    return ((int)u >= 0) ? (u | 0x80000000u) : ~u;
}
__device__ __forceinline__ float dec_max(unsigned u) {
    return (u & 0x80000000u) ? __uint_as_float(u ^ 0x80000000u)
                             : __uint_as_float(~u);
}

__device__ __forceinline__ float leaky(float v) {
    return v > 0.f ? v : LEAKY * v;
}

// fp32 -> bf16 (round-to-nearest-even), finite inputs
__device__ __forceinline__ unsigned short f2bf(float f) {
    unsigned u = __float_as_uint(f);
    u = (u + 0x7FFFu + ((u >> 16) & 1u)) >> 16;
    return (unsigned short)u;
}
__device__ __forceinline__ float bf2f(unsigned short u) {
    return __uint_as_float(((unsigned)u) << 16);
}

// ============================================================
// F1: fused GEMM (blocks 0..K1B-1) || edge bucketing (blocks K1B..+FB-1).
// Disjoint inputs (x/W/a vs edge_index); fusion forces concurrent
// execution (R3: F1+F2 fusions worth ~17-21us vs serial dispatches).
// h is stored HEAD-MAJOR: hb[head][node][32ch] so the per-head pull
// passes gather from a contiguous 3.2MB slice (fits per-XCD 4MiB L2).
// ============================================================
struct FillSh { int est[FCH]; int hist[NB]; int rbase[NB]; };  // ~19.5 KB
union F1Sh { unsigned short Wl[32 * 64 * 8]; FillSh fl; };     // 32 KB

__global__ __launch_bounds__(256) void f1_gemm_fill(
    const float* __restrict__ x, const float* __restrict__ W,
    const float* __restrict__ a_src, const float* __restrict__ a_tgt,
    const int* __restrict__ src, const int* __restrict__ tgt,
    int* __restrict__ bcur, int* __restrict__ ebkt,
    unsigned short* __restrict__ hb, float* __restrict__ s,
    float* __restrict__ t)
{
    __shared__ F1Sh sh;
    const int tid = threadIdx.x;

    if (blockIdx.x >= K1B) {
        // ---------------- kb_fill path ----------------
        int* est   = sh.fl.est;
        int* hist  = sh.fl.hist;
        int* rbase = sh.fl.rbase;
        int beg = (blockIdx.x - K1B) * FCH;
        int cnt = min(beg + FCH, E_EDGES) - beg;
        for (int i = tid; i < NB; i += 256) hist[i] = 0;
        __syncthreads();
        for (int j = tid; j < cnt; j += 256) {
            int sv = src[beg + j], tv = tgt[beg + j];   // both < 65536
            est[j] = sv | (tv << 16);
            atomicAdd(&hist[tv >> BSH], 1);
        }
        __syncthreads();
        for (int i = tid; i < NB; i += 256) {
            int c = hist[i];
            if (c) {
                int r = atomicAdd(&bcur[i], c);
                rbase[i] = i * PCAP + min(r, PCAP);
            }
        }
        __syncthreads();
        for (int i = tid; i < NB; i += 256) hist[i] = 0;  // reuse as cursor
        __syncthreads();
        for (int j = tid; j < cnt; j += 256) {
            int p  = est[j];
            int tv = (int)((unsigned)p >> 16);
            int b  = tv >> BSH;
            int off = atomicAdd(&hist[b], 1);
            int idx = rbase[b] + off;
            if (idx < (b + 1) * PCAP)             // overflow guard (never hits)
                ebkt[idx] = (p & 0xFFFF) | ((tv & 127) << 16);
        }
        return;
    }

    // ---------------- k1 GEMM path ----------------
    // W staged into LDS pre-swizzled into B-fragment layout (32 KB).
    // (R0/R1 A/B: strided stage is latency-hidden, keep in-block.)
    unsigned short* Wl = sh.Wl;
    for (int idx = tid; idx < 2048; idx += 256) {
        int l  = idx & 63;
        int f  = idx >> 6;
        int nt = f >> 2, kc = f & 3;
        int kbase = kc * 32 + ((l >> 4) << 3);
        int col   = nt * 16 + (l & 15);
        unsigned short* dst = &Wl[idx * 8];
#pragma unroll
        for (int j = 0; j < 8; j++)
            dst[j] = f2bf(W[(kbase + j) * HD + col]);
    }
    __syncthreads();

    const int wave = tid >> 6, lane = tid & 63;
    const int quad = lane >> 4, rl = lane & 15;
    const int row0 = blockIdx.x * 64 + wave * 16;
    const int crow = min(row0 + rl, N_NODES - 1);

    short8 a[4];
    const float* xp = x + (size_t)crow * IN_DIM + quad * 8;
#pragma unroll
    for (int kc = 0; kc < 4; kc++) {
        float4 v0 = *(const float4*)(xp + kc * 32);
        float4 v1 = *(const float4*)(xp + kc * 32 + 4);
        short8 av;
        av[0] = (short)f2bf(v0.x); av[1] = (short)f2bf(v0.y);
        av[2] = (short)f2bf(v0.z); av[3] = (short)f2bf(v0.w);
        av[4] = (short)f2bf(v1.x); av[5] = (short)f2bf(v1.y);
        av[6] = (short)f2bf(v1.z); av[7] = (short)f2bf(v1.w);
        a[kc] = av;
    }

    float asv[8], atv[8];
#pragma unroll
    for (int nt = 0; nt < 8; nt++) {
        asv[nt] = a_src[nt * 16 + rl];
        atv[nt] = a_tgt[nt * 16 + rl];
    }

    float ps[4][4], pt[4][4];   // [head][r]
#pragma unroll
    for (int hh = 0; hh < 4; hh++)
#pragma unroll
        for (int r = 0; r < 4; r++) { ps[hh][r] = 0.f; pt[hh][r] = 0.f; }

#pragma unroll
    for (int nt = 0; nt < 8; nt++) {
        f32x4 acc = {0.f, 0.f, 0.f, 0.f};
#pragma unroll
        for (int kc = 0; kc < 4; kc++) {
            short8 b = *(const short8*)&Wl[((nt * 4 + kc) * 64 + lane) * 8];
            acc = __builtin_amdgcn_mfma_f32_16x16x32_bf16(a[kc], b, acc, 0, 0, 0);
        }
        const int hh   = nt >> 1;
        const int colh = (nt & 1) * 16 + rl;   // 0..31 within head slice
#pragma unroll
        for (int r = 0; r < 4; r++) {
            int orow = row0 + quad * 4 + r;
            if (orow < N_NODES)
                hb[(size_t)hh * HSL + (size_t)orow * 32 + colh] = f2bf(acc[r]);
            ps[hh][r] = fmaf(acc[r], asv[nt], ps[hh][r]);
            pt[hh][r] = fmaf(acc[r], atv[nt], pt[hh][r]);
        }
    }

#pragma unroll
    for (int m = 1; m <= 8; m <<= 1) {
#pragma unroll
        for (int hh = 0; hh < 4; hh++)
#pragma unroll
            for (int r = 0; r < 4; r++) {
                ps[hh][r] += __shfl_xor(ps[hh][r], m, 64);
                pt[hh][r] += __shfl_xor(pt[hh][r], m, 64);
            }
    }
    if (rl == 0) {
#pragma unroll
        for (int r = 0; r < 4; r++) {
            int orow = row0 + quad * 4 + r;
            if (orow < N_NODES) {
#pragma unroll
                for (int hh = 0; hh < 4; hh++) {
                    s[orow * HEADS + hh] = ps[hh][r];
                    t[orow * HEADS + hh] = pt[hh][r];
                }
            }
        }
    }
}

// ============================================================
// F2: fused bucket fine-sort (blocks 0..NB-1) || per-head node max
// (blocks NB..NB+K2_BLOCKS-1). Src-chunk coarse sort REMOVED (R3
// analysis: the per-target scatter destroys src order, so it never
// helped k4 -- it was 2 extra LDS passes + 2048 atomics per block).
// ============================================================
struct SortSh {
    int ebl[PCAP]; int csc[NB + 1];
    int deg_l[128]; int excl_l[128]; int cur_l[128];
    int wtot;
};                                                             // ~13.3 KB
union F2Sh { SortSh so; float red[4][8]; };

__global__ __launch_bounds__(256) void f2_sort_max(
    const int* __restrict__ bcur, const int* __restrict__ ebkt,
    int* __restrict__ rowptr, unsigned short* __restrict__ esrc,
    const float* __restrict__ s, const float* __restrict__ t,
    unsigned* __restrict__ smax, unsigned* __restrict__ tmax)
{
    __shared__ F2Sh sh;
    int tid  = threadIdx.x;
    int lane = tid & 63, wv = tid >> 6;

    if (blockIdx.x >= NB) {
        // ---------------- k2 node-max path ----------------
        int bI = blockIdx.x - NB;
        float sm0 = -INFINITY, sm1 = -INFINITY, sm2 = -INFINITY, sm3 = -INFINITY;
        float tm0 = -INFINITY, tm1 = -INFINITY, tm2 = -INFINITY, tm3 = -INFINITY;
        for (int n = bI * 256 + tid; n < N_NODES; n += K2_BLOCKS * 256) {
            float4 s4 = ((const float4*)s)[n];
            float4 t4 = ((const float4*)t)[n];
            sm0 = fmaxf(sm0, s4.x); sm1 = fmaxf(sm1, s4.y);
            sm2 = fmaxf(sm2, s4.z); sm3 = fmaxf(sm3, s4.w);
            tm0 = fmaxf(tm0, t4.x); tm1 = fmaxf(tm1, t4.y);
            tm2 = fmaxf(tm2, t4.z); tm3 = fmaxf(tm3, t4.w);
        }
#pragma unroll
        for (int m = 32; m >= 1; m >>= 1) {
            sm0 = fmaxf(sm0, __shfl_xor(sm0, m, 64));
            sm1 = fmaxf(sm1, __shfl_xor(sm1, m, 64));
            sm2 = fmaxf(sm2, __shfl_xor(sm2, m, 64));
            sm3 = fmaxf(sm3, __shfl_xor(sm3, m, 64));
            tm0 = fmaxf(tm0, __shfl_xor(tm0, m, 64));
            tm1 = fmaxf(tm1, __shfl_xor(tm1, m, 64));
            tm2 = fmaxf(tm2, __shfl_xor(tm2, m, 64));
            tm3 = fmaxf(tm3, __shfl_xor(tm3, m, 64));
        }
        if (lane == 0) {
            sh.red[wv][0] = sm0; sh.red[wv][1] = sm1;
            sh.red[wv][2] = sm2; sh.red[wv][3] = sm3;
            sh.red[wv][4] = tm0; sh.red[wv][5] = tm1;
            sh.red[wv][6] = tm2; sh.red[wv][7] = tm3;
        }
        __syncthreads();
        if (tid < 8) {
            float v = fmaxf(fmaxf(sh.red[0][tid], sh.red[1][tid]),
                            fmaxf(sh.red[2][tid], sh.red[3][tid]));
            unsigned* dst = (tid < 4) ? &smax[tid] : &tmax[tid - 4];
            atomicMax(dst, enc_max(v));
        }
        return;
    }

    // ---------------- bucket fine-sort path ----------------
    int b = blockIdx.x;
    int* ebl    = sh.so.ebl;
    int* csc    = sh.so.csc;
    int* deg_l  = sh.so.deg_l;
    int* excl_l = sh.so.excl_l;
    int* cur_l  = sh.so.cur_l;

    for (int i = tid; i < NB; i += 256) csc[i] = min(bcur[i], PCAP);
    if (tid < 128) { deg_l[tid] = 0; cur_l[tid] = 0; }
    __syncthreads();
    // wave-0 chunked exclusive scan of csc[0..NB)
    if (tid < 64) {
        int cb = tid * SCCH;
        int loc[SCCH];
        int sum = 0;
#pragma unroll
        for (int k = 0; k < SCCH; k++) {
            int idx = cb + k;
            int v = (idx < NB) ? csc[idx] : 0;
            loc[k] = sum; sum += v;
        }
        int ss = sum;
#pragma unroll
        for (int off = 1; off < 64; off <<= 1) {
            int u = __shfl_up(ss, off, 64);
            if (tid >= off) ss += u;
        }
        int excl = ss - sum;
#pragma unroll
        for (int k = 0; k < SCCH; k++) {
            int idx = cb + k;
            if (idx < NB) csc[idx] = excl + loc[k];
        }
        if (tid == 63) {
            csc[NB] = excl + sum;             // == E_EDGES
            if (b == 0) rowptr[N_NODES] = excl + sum;
        }
    }
    __syncthreads();
    int base_in = b * PCAP;
    int base    = csc[b];
    int cnt     = csc[b + 1] - base;          // <= PCAP

    // stage + per-target degree histogram
    for (int j = tid; j < cnt; j += 256) {
        int p = ebkt[base_in + j];
        ebl[j] = p;
        atomicAdd(&deg_l[p >> 16], 1);
    }
    __syncthreads();

    // exclusive scan of 128 target degrees
    int v = (tid < 128) ? deg_l[tid] : 0;
    int sv2 = v;
#pragma unroll
    for (int off = 1; off < 64; off <<= 1) {
        int u = __shfl_up(sv2, off, 64);
        if (lane >= off) sv2 += u;
    }
    if (tid == 63) sh.so.wtot = sv2;
    __syncthreads();
    if (tid < 128) {
        int ex = sv2 - v + ((wv == 1) ? sh.so.wtot : 0);
        excl_l[tid] = ex;
        int node = (b << BSH) + tid;
        if (node < N_NODES) rowptr[node] = base + ex;
    }
    __syncthreads();
    for (int j = tid; j < cnt; j += 256) {
        int p  = ebl[j];
        int tl = p >> 16;
        int off = atomicAdd(&cur_l[tl], 1);
        esrc[base + excl_l[tl] + off] = (unsigned short)(p & 0xFFFF);
    }
}

// ============================================================
// K4H: per-head pull pass. 4 lanes per node, 8 bf16 ch each (16 B).
// hb is head-major: pass h gathers only from a contiguous 3.2 MB slice
// -> fits per-XCD 4 MiB L2, so the ~51 MB/pass of logical gather is
// L2-hit after slice fill (R3 theory: monolithic k4's 256B-row gather
// missed L2 everywhere: 205 MB on the L3/HBM path = its 46 us).
// Per edge: ONE 64B line (was 4). Barrier-free; 4-wide edge chunks
// with clamped tail; dual accumulators.
// ============================================================
__global__ __launch_bounds__(256) void k4_pull_head(
    const int* __restrict__ rowptr, const unsigned short* __restrict__ esrc,
    const float* __restrict__ s, const float* __restrict__ t,
    const unsigned* __restrict__ smax, const unsigned* __restrict__ tmax,
    const unsigned short* __restrict__ hb, unsigned short* __restrict__ outpb,
    int head)
{
    int g = blockIdx.x * 256 + threadIdx.x;
    int node = g >> 2;
    int lane = g & 3;                     // 4 lanes/node, 8 ch each
    if (node >= N_NODES) return;
    int beg = rowptr[node];
    int end = rowptr[node + 1];
    float mx = leaky(dec_max(smax[head]) + dec_max(tmax[head]));
    float tv = t[node * HEADS + head];

    float p0 = 0.f, p1 = 0.f, p2 = 0.f, p3 = 0.f;
    float p4 = 0.f, p5 = 0.f, p6 = 0.f, p7 = 0.f, psum = 0.f;
    float q0 = 0.f, q1 = 0.f, q2 = 0.f, q3 = 0.f;
    float q4 = 0.f, q5 = 0.f, q6 = 0.f, q7 = 0.f, qsum = 0.f;
    const unsigned short* hsl = hb + (size_t)head * HSL + lane * 8;

    for (int j = beg; j < end; j += 4) {
        int lim = end - j;                // >= 1
        int si[4];
#pragma unroll
        for (int u = 0; u < 4; u++) {
            int uu = (u < lim) ? u : (lim - 1);
            si[u] = esrc[j + uu];
        }
        float sv[4];
        us8 hv[4];
#pragma unroll
        for (int u = 0; u < 4; u++) {
            sv[u] = s[si[u] * HEADS + head];
            hv[u] = *(const us8*)(hsl + (size_t)si[u] * 32);
        }
        float al[4];
#pragma unroll
        for (int u = 0; u < 4; u++) {
            float a = __expf(leaky(sv[u] + tv) - mx);
            al[u] = (u < lim) ? a : 0.f;
        }
#pragma unroll
        for (int u = 0; u < 4; u += 2) {
            float a0 = al[u], a1 = al[u + 1];
            p0 = fmaf(a0, bf2f(hv[u][0]), p0);  q0 = fmaf(a1, bf2f(hv[u+1][0]), q0);
            p1 = fmaf(a0, bf2f(hv[u][1]), p1);  q1 = fmaf(a1, bf2f(hv[u+1][1]), q1);
            p2 = fmaf(a0, bf2f(hv[u][2]), p2);  q2 = fmaf(a1, bf2f(hv[u+1][2]), q2);
            p3 = fmaf(a0, bf2f(hv[u][3]), p3);  q3 = fmaf(a1, bf2f(hv[u+1][3]), q3);
            p4 = fmaf(a0, bf2f(hv[u][4]), p4);  q4 = fmaf(a1, bf2f(hv[u+1][4]), q4);
            p5 = fmaf(a0, bf2f(hv[u][5]), p5);  q5 = fmaf(a1, bf2f(hv[u+1][5]), q5);
            p6 = fmaf(a0, bf2f(hv[u][6]), p6);  q6 = fmaf(a1, bf2f(hv[u+1][6]), q6);
            p7 = fmaf(a0, bf2f(hv[u][7]), p7);  q7 = fmaf(a1, bf2f(hv[u+1][7]), q7);
            psum += a0; qsum += a1;
        }
    }

    float w = 1.0f / (psum + qsum + 1e-16f);
    us8 o;
    o[0] = f2bf((p0 + q0) * w); o[1] = f2bf((p1 + q1) * w);
    o[2] = f2bf((p2 + q2) * w); o[3] = f2bf((p3 + q3) * w);
    o[4] = f2bf((p4 + q4) * w); o[5] = f2bf((p5 + q5) * w);
    o[6] = f2bf((p6 + q6) * w); o[7] = f2bf((p7 + q7) * w);
    *(us8*)(outpb + (size_t)node * HD + head * 32 + lane * 8) = o;
}

// ============================================================
// K5: BN stats from bf16 outp: per-channel sum & sumsq
// ============================================================
__global__ __launch_bounds__(256) void k5_stats(
    const unsigned short* __restrict__ outpb,
    float* __restrict__ bnsum, float* __restrict__ bnsq)
{
    __shared__ float lsum[HD], lsq[HD];
    int c8  = threadIdx.x & 15;          // channel octet
    int grp = threadIdx.x >> 4;          // row subgroup 0..15
    if (threadIdx.x < HD) { lsum[threadIdx.x] = 0.f; lsq[threadIdx.x] = 0.f; }
    __syncthreads();
    int base = blockIdx.x * 256;
    int end  = min(base + 256, N_NODES);
    float sm[8], sq[8];
#pragma unroll
    for (int i = 0; i < 8; i++) { sm[i] = 0.f; sq[i] = 0.f; }
    for (int r = base + grp; r < end; r += 16) {
        us8 v = *(const us8*)(outpb + (size_t)r * HD + c8 * 8);
#pragma unroll
        for (int i = 0; i < 8; i++) {
            float f = bf2f(v[i]);
            sm[i] += f;
            sq[i] = fmaf(f, f, sq[i]);
        }
    }
#pragma unroll
    for (int i = 0; i < 8; i++) {
        atomicAdd(&lsum[c8 * 8 + i], sm[i]);
        atomicAdd(&lsq[c8 * 8 + i], sq[i]);
    }
    __syncthreads();
    if (threadIdx.x < HD) {
        unsafeAtomicAdd(&bnsum[threadIdx.x], lsum[threadIdx.x]);
        unsafeAtomicAdd(&bnsq[threadIdx.x], lsq[threadIdx.x]);
    }
}

// ============================================================
// K6: BN apply (bf16 in, fp32 out) -> d_out
// ============================================================
__global__ __launch_bounds__(256) void k6_apply(
    const unsigned short* __restrict__ outpb,
    const float* __restrict__ bnsum, const float* __restrict__ bnsq,
    const float* __restrict__ gamma, const float* __restrict__ beta,
    float* __restrict__ out)
{
    int c8  = threadIdx.x & 15;
    int grp = threadIdx.x >> 4;
    int base = blockIdx.x * 256;
    int end  = min(base + 256, N_NODES);
    float inv_n = 1.0f / (float)N_NODES;
    float scale[8], shift[8];
#pragma unroll
    for (int i = 0; i < 8; i++) {
        int c = c8 * 8 + i;
        float mean = bnsum[c] * inv_n;
        float var  = bnsq[c] * inv_n - mean * mean;
        float sc   = gamma[c] * rsqrtf(var + BN_EPS);
        scale[i] = sc;
        shift[i] = beta[c] - mean * sc;
    }
    for (int r = base + grp; r < end; r += 16) {
        us8 v = *(const us8*)(outpb + (size_t)r * HD + c8 * 8);
        float4 o0, o1;
        o0.x = fmaf(bf2f(v[0]), scale[0], shift[0]);
        o0.y = fmaf(bf2f(v[1]), scale[1], shift[1]);
        o0.z = fmaf(bf2f(v[2]), scale[2], shift[2]);
        o0.w = fmaf(bf2f(v[3]), scale[3], shift[3]);
        o1.x = fmaf(bf2f(v[4]), scale[4], shift[4]);
        o1.y = fmaf(bf2f(v[5]), scale[5], shift[5]);
        o1.z = fmaf(bf2f(v[6]), scale[6], shift[6]);
        o1.w = fmaf(bf2f(v[7]), scale[7], shift[7]);
        float* op = out + (size_t)r * HD + c8 * 8;
        ((float4*)op)[0] = o0;
        ((float4*)op)[1] = o1;
    }
}

// ============================================================
extern "C" void kernel_launch(void* const* d_in, const int* in_sizes, int n_in,
                              void* d_out, int out_size, void* d_ws, size_t ws_size,
                              hipStream_t stream)
{
    const float* x     = (const float*)d_in[0];
    const float* W     = (const float*)d_in[1];
    const float* a_src = (const float*)d_in[2];
    const float* a_tgt = (const float*)d_in[3];
    const float* gamma = (const float*)d_in[4];
    const float* beta  = (const float*)d_in[5];
    const int*   eidx  = (const int*)d_in[6];
    const int* src = eidx;
    const int* tgt = eidx + E_EDGES;
    float* out = (float*)d_out;

    // workspace layout
    unsigned short* hb    = (unsigned short*)d_ws;          // 6.4M ushort (head-major)
    float*          s     = (float*)d_ws + 3200000;         // 200K float
    float*          t     = s + (size_t)N_NODES * HEADS;    // 200K float
    unsigned short* outpb = (unsigned short*)(t + (size_t)N_NODES * HEADS); // 6.4M us
    int*            ebkt  = (int*)outpb;                    // NB*PCAP=1.0M int (aliases outpb)
    unsigned short* esrc  = outpb + 6400000;                // 800K ushort
    int*            rowptr= (int*)(esrc + E_EDGES);         // 50,001 int
    // ---- zero-init region (single memset) ----
    int*      bcur  = rowptr + N_NODES + 1;                 // 392
    unsigned* smax  = (unsigned*)(bcur + 392);              // 4
    unsigned* tmax  = smax + 4;                             // 4
    float*    bnsum = (float*)(tmax + 4);                   // 128
    float*    bnsq  = bnsum + HD;                           // 128
    size_t zero_bytes = (392 + 8 + HD + HD) * 4;
    hipMemsetAsync(bcur, 0, zero_bytes, stream);

    // F1: GEMM || edge bucketing (independent inputs, forced overlap)
    f1_gemm_fill<<<K1B + FB, 256, 0, stream>>>(x, W, a_src, a_tgt,
                                               src, tgt, bcur, ebkt,
                                               hb, s, t);
    // F2: bucket fine-sort || per-head node max
    f2_sort_max<<<NB + K2_BLOCKS, 256, 0, stream>>>(bcur, ebkt, rowptr, esrc,
                                                    s, t, smax, tmax);
    // per-head pull passes (sequential: keeps gather slice L2-resident)
    for (int h = 0; h < HEADS; ++h)
        k4_pull_head<<<(N_NODES * 4 + 255) / 256, 256, 0, stream>>>(
            rowptr, esrc, s, t, smax, tmax, hb, outpb, h);
    // BN
    k5_stats<<<(N_NODES + 255) / 256, 256, 0, stream>>>(outpb, bnsum, bnsq);
    k6_apply<<<(N_NODES + 255) / 256, 256, 0, stream>>>(outpb, bnsum, bnsq,
                                                        gamma, beta, out);
}

// Round 5
// 178.114 us; speedup vs baseline: 1.1682x; 1.1682x over previous
//
#include <hip/hip_runtime.h>
#include <math.h>

#define N_NODES 50000
#define E_EDGES 800000
#define IN_DIM 128
#define HEADS 4
#define OUT_DIM 32
#define HD 128          // HEADS*OUT_DIM
#define LEAKY 0.4f
#define BN_EPS 1e-5f

// bucketed counting sort params: bucket = tgt >> 7 (128 targets/bucket)
#define BSH 7
#define NB ((N_NODES + 127) >> BSH)     // 391
#define FB 196                           // kb_fill block count
#define FCH 4096                         // edges per kb_fill block
#define PCAP 2560                        // padded bucket capacity (mean 2048, sd 45)
#define SCCH ((NB + 63) / 64)            // 7: scan chunk per lane
#define K1B ((N_NODES + 63) / 64)        // 782 GEMM blocks
#define K2_BLOCKS 32

typedef __attribute__((ext_vector_type(8))) short short8;
typedef __attribute__((ext_vector_type(8))) unsigned short us8;
typedef __attribute__((ext_vector_type(4))) float f32x4;

// ---- monotonic float<->uint encoding for atomicMax on floats ----
__device__ __forceinline__ unsigned enc_max(float f) {
    unsigned u = __float_as_uint(f);
    return ((int)u >= 0) ? (u | 0x80000000u) : ~u;
}
__device__ __forceinline__ float dec_max(unsigned u) {
    return (u & 0x80000000u) ? __uint_as_float(u ^ 0x80000000u)
                             : __uint_as_float(~u);
}

__device__ __forceinline__ float leaky(float v) {
    return v > 0.f ? v : LEAKY * v;
}

// fp32 -> bf16 (round-to-nearest-even), finite inputs
__device__ __forceinline__ unsigned short f2bf(float f) {
    unsigned u = __float_as_uint(f);
    u = (u + 0x7FFFu + ((u >> 16) & 1u)) >> 16;
    return (unsigned short)u;
}
__device__ __forceinline__ float bf2f(unsigned short u) {
    return __uint_as_float(((unsigned)u) << 16);
}

// ============================================================
// F1: fused GEMM (blocks 0..K1B-1) || edge bucketing (blocks K1B..).
// Disjoint inputs; fusion forces concurrent execution (R3: worth
// ~17-21us vs serial dispatches).
// Fill path now does an IN-LDS counting sort by bucket before writing
// ebkt, so the 800K previously-scattered 4B writes (~51MB of 64B-line
// traffic) become coalesced ~10-edge runs (~7MB effective).
// hb layout: node-major [node][128] (R4 lesson: head-major + per-head
// passes starves occupancy; monolithic pull needs node-major).
// ============================================================
struct FillSh {
    int est[FCH];                 // staged packed edges (src | tgt<<16)
    int srt[FCH];                 // bucket-sorted copy
    int hist[NB];                 // count -> cursor
    int lsc[NB];                  // exclusive scan (preserved)
    int rbase[NB];                // reserved global run base
};                                // 16+16+4.7 KB ~= 36.8 KB
union F1Sh { unsigned short Wl[32 * 64 * 8]; FillSh fl; };

__global__ __launch_bounds__(256) void f1_gemm_fill(
    const float* __restrict__ x, const float* __restrict__ W,
    const float* __restrict__ a_src, const float* __restrict__ a_tgt,
    const int* __restrict__ src, const int* __restrict__ tgt,
    int* __restrict__ bcur, int* __restrict__ ebkt,
    unsigned short* __restrict__ hb, float* __restrict__ s,
    float* __restrict__ t)
{
    __shared__ F1Sh sh;
    const int tid = threadIdx.x;

    if (blockIdx.x >= K1B) {
        // ---------------- fill path ----------------
        int* est   = sh.fl.est;
        int* srt   = sh.fl.srt;
        int* hist  = sh.fl.hist;
        int* lsc   = sh.fl.lsc;
        int* rbase = sh.fl.rbase;
        int beg = (blockIdx.x - K1B) * FCH;
        int cnt = min(beg + FCH, E_EDGES) - beg;
        for (int i = tid; i < NB; i += 256) hist[i] = 0;
        __syncthreads();
        for (int j = tid; j < cnt; j += 256) {
            int sv = src[beg + j], tv = tgt[beg + j];   // both < 65536
            est[j] = sv | (tv << 16);
            atomicAdd(&hist[tv >> BSH], 1);
        }
        __syncthreads();
        // reserve global runs + wave-0 exclusive scan of hist
        for (int i = tid; i < NB; i += 256) {
            int c = hist[i];
            if (c) {
                int r = atomicAdd(&bcur[i], c);
                rbase[i] = i * PCAP + min(r, PCAP);
            }
        }
        if (tid < 64) {
            int cb = tid * SCCH;
            int loc[SCCH];
            int sum = 0;
#pragma unroll
            for (int k = 0; k < SCCH; k++) {
                int idx = cb + k;
                int v = (idx < NB) ? hist[idx] : 0;
                loc[k] = sum; sum += v;
            }
            int ss = sum;
#pragma unroll
            for (int off = 1; off < 64; off <<= 1) {
                int u = __shfl_up(ss, off, 64);
                if (tid >= off) ss += u;
            }
            int excl = ss - sum;
#pragma unroll
            for (int k = 0; k < SCCH; k++) {
                int idx = cb + k;
                if (idx < NB) lsc[idx] = excl + loc[k];
            }
        }
        __syncthreads();
        // cursor init + LDS scatter into bucket-sorted order
        for (int i = tid; i < NB; i += 256) hist[i] = lsc[i];
        __syncthreads();
        for (int j = tid; j < cnt; j += 256) {
            int p = est[j];
            int pos = atomicAdd(&hist[(int)((unsigned)p >> 16) >> BSH], 1);
            srt[pos] = p;
        }
        __syncthreads();
        // coalesced run writes: consecutive tids -> adjacent addresses
        for (int j = tid; j < cnt; j += 256) {
            int p  = srt[j];
            int tv = (int)((unsigned)p >> 16);
            int b  = tv >> BSH;
            int idx = rbase[b] + (j - lsc[b]);
            if (idx < (b + 1) * PCAP)             // overflow guard (never hits)
                ebkt[idx] = (p & 0xFFFF) | ((tv & 127) << 16);
        }
        return;
    }

    // ---------------- GEMM path ----------------
    // W staged into LDS pre-swizzled into B-fragment layout (32 KB).
    unsigned short* Wl = sh.Wl;
    for (int idx = tid; idx < 2048; idx += 256) {
        int l  = idx & 63;
        int f  = idx >> 6;
        int nt = f >> 2, kc = f & 3;
        int kbase = kc * 32 + ((l >> 4) << 3);
        int col   = nt * 16 + (l & 15);
        unsigned short* dst = &Wl[idx * 8];
#pragma unroll
        for (int j = 0; j < 8; j++)
            dst[j] = f2bf(W[(kbase + j) * HD + col]);
    }
    __syncthreads();

    const int wave = tid >> 6, lane = tid & 63;
    const int quad = lane >> 4, rl = lane & 15;
    const int row0 = blockIdx.x * 64 + wave * 16;
    const int crow = min(row0 + rl, N_NODES - 1);

    short8 a[4];
    const float* xp = x + (size_t)crow * IN_DIM + quad * 8;
#pragma unroll
    for (int kc = 0; kc < 4; kc++) {
        float4 v0 = *(const float4*)(xp + kc * 32);
        float4 v1 = *(const float4*)(xp + kc * 32 + 4);
        short8 av;
        av[0] = (short)f2bf(v0.x); av[1] = (short)f2bf(v0.y);
        av[2] = (short)f2bf(v0.z); av[3] = (short)f2bf(v0.w);
        av[4] = (short)f2bf(v1.x); av[5] = (short)f2bf(v1.y);
        av[6] = (short)f2bf(v1.z); av[7] = (short)f2bf(v1.w);
        a[kc] = av;
    }

    float asv[8], atv[8];
#pragma unroll
    for (int nt = 0; nt < 8; nt++) {
        asv[nt] = a_src[nt * 16 + rl];
        atv[nt] = a_tgt[nt * 16 + rl];
    }

    float ps[4][4], pt[4][4];   // [head][r]
#pragma unroll
    for (int hh = 0; hh < 4; hh++)
#pragma unroll
        for (int r = 0; r < 4; r++) { ps[hh][r] = 0.f; pt[hh][r] = 0.f; }

#pragma unroll
    for (int nt = 0; nt < 8; nt++) {
        f32x4 acc = {0.f, 0.f, 0.f, 0.f};
#pragma unroll
        for (int kc = 0; kc < 4; kc++) {
            short8 b = *(const short8*)&Wl[((nt * 4 + kc) * 64 + lane) * 8];
            acc = __builtin_amdgcn_mfma_f32_16x16x32_bf16(a[kc], b, acc, 0, 0, 0);
        }
        const int ocol = nt * 16 + rl;
        const int hh   = nt >> 1;
#pragma unroll
        for (int r = 0; r < 4; r++) {
            int orow = row0 + quad * 4 + r;
            if (orow < N_NODES)
                hb[(size_t)orow * HD + ocol] = f2bf(acc[r]);
            ps[hh][r] = fmaf(acc[r], asv[nt], ps[hh][r]);
            pt[hh][r] = fmaf(acc[r], atv[nt], pt[hh][r]);
        }
    }

#pragma unroll
    for (int m = 1; m <= 8; m <<= 1) {
#pragma unroll
        for (int hh = 0; hh < 4; hh++)
#pragma unroll
            for (int r = 0; r < 4; r++) {
                ps[hh][r] += __shfl_xor(ps[hh][r], m, 64);
                pt[hh][r] += __shfl_xor(pt[hh][r], m, 64);
            }
    }
    if (rl == 0) {
#pragma unroll
        for (int r = 0; r < 4; r++) {
            int orow = row0 + quad * 4 + r;
            if (orow < N_NODES) {
#pragma unroll
                for (int hh = 0; hh < 4; hh++) {
                    s[orow * HEADS + hh] = ps[hh][r];
                    t[orow * HEADS + hh] = pt[hh][r];
                }
            }
        }
    }
}

// ============================================================
// F2: fused bucket fine-sort (blocks 0..NB-1) || per-head node max
// (blocks NB..NB+K2_BLOCKS-1). Src coarse sort removed (R4: provably
// dead -- the per-target scatter destroys src order).
// ============================================================
struct SortSh {
    int ebl[PCAP]; int csc[NB + 1];
    int deg_l[128]; int excl_l[128]; int cur_l[128];
    int wtot;
};                                                             // ~13.3 KB
union F2Sh { SortSh so; float red[4][8]; };

__global__ __launch_bounds__(256) void f2_sort_max(
    const int* __restrict__ bcur, const int* __restrict__ ebkt,
    int* __restrict__ rowptr, unsigned short* __restrict__ esrc,
    const float* __restrict__ s, const float* __restrict__ t,
    unsigned* __restrict__ smax, unsigned* __restrict__ tmax)
{
    __shared__ F2Sh sh;
    int tid  = threadIdx.x;
    int lane = tid & 63, wv = tid >> 6;

    if (blockIdx.x >= NB) {
        // ---------------- node-max path ----------------
        int bI = blockIdx.x - NB;
        float sm0 = -INFINITY, sm1 = -INFINITY, sm2 = -INFINITY, sm3 = -INFINITY;
        float tm0 = -INFINITY, tm1 = -INFINITY, tm2 = -INFINITY, tm3 = -INFINITY;
        for (int n = bI * 256 + tid; n < N_NODES; n += K2_BLOCKS * 256) {
            float4 s4 = ((const float4*)s)[n];
            float4 t4 = ((const float4*)t)[n];
            sm0 = fmaxf(sm0, s4.x); sm1 = fmaxf(sm1, s4.y);
            sm2 = fmaxf(sm2, s4.z); sm3 = fmaxf(sm3, s4.w);
            tm0 = fmaxf(tm0, t4.x); tm1 = fmaxf(tm1, t4.y);
            tm2 = fmaxf(tm2, t4.z); tm3 = fmaxf(tm3, t4.w);
        }
#pragma unroll
        for (int m = 32; m >= 1; m >>= 1) {
            sm0 = fmaxf(sm0, __shfl_xor(sm0, m, 64));
            sm1 = fmaxf(sm1, __shfl_xor(sm1, m, 64));
            sm2 = fmaxf(sm2, __shfl_xor(sm2, m, 64));
            sm3 = fmaxf(sm3, __shfl_xor(sm3, m, 64));
            tm0 = fmaxf(tm0, __shfl_xor(tm0, m, 64));
            tm1 = fmaxf(tm1, __shfl_xor(tm1, m, 64));
            tm2 = fmaxf(tm2, __shfl_xor(tm2, m, 64));
            tm3 = fmaxf(tm3, __shfl_xor(tm3, m, 64));
        }
        if (lane == 0) {
            sh.red[wv][0] = sm0; sh.red[wv][1] = sm1;
            sh.red[wv][2] = sm2; sh.red[wv][3] = sm3;
            sh.red[wv][4] = tm0; sh.red[wv][5] = tm1;
            sh.red[wv][6] = tm2; sh.red[wv][7] = tm3;
        }
        __syncthreads();
        if (tid < 8) {
            float v = fmaxf(fmaxf(sh.red[0][tid], sh.red[1][tid]),
                            fmaxf(sh.red[2][tid], sh.red[3][tid]));
            unsigned* dst = (tid < 4) ? &smax[tid] : &tmax[tid - 4];
            atomicMax(dst, enc_max(v));
        }
        return;
    }

    // ---------------- bucket fine-sort path ----------------
    int b = blockIdx.x;
    int* ebl    = sh.so.ebl;
    int* csc    = sh.so.csc;
    int* deg_l  = sh.so.deg_l;
    int* excl_l = sh.so.excl_l;
    int* cur_l  = sh.so.cur_l;

    for (int i = tid; i < NB; i += 256) csc[i] = min(bcur[i], PCAP);
    if (tid < 128) { deg_l[tid] = 0; cur_l[tid] = 0; }
    __syncthreads();
    // wave-0 chunked exclusive scan of csc[0..NB)
    if (tid < 64) {
        int cb = tid * SCCH;
        int loc[SCCH];
        int sum = 0;
#pragma unroll
        for (int k = 0; k < SCCH; k++) {
            int idx = cb + k;
            int v = (idx < NB) ? csc[idx] : 0;
            loc[k] = sum; sum += v;
        }
        int ss = sum;
#pragma unroll
        for (int off = 1; off < 64; off <<= 1) {
            int u = __shfl_up(ss, off, 64);
            if (tid >= off) ss += u;
        }
        int excl = ss - sum;
#pragma unroll
        for (int k = 0; k < SCCH; k++) {
            int idx = cb + k;
            if (idx < NB) csc[idx] = excl + loc[k];
        }
        if (tid == 63) {
            csc[NB] = excl + sum;             // == E_EDGES
            if (b == 0) rowptr[N_NODES] = excl + sum;
        }
    }
    __syncthreads();
    int base_in = b * PCAP;
    int base    = csc[b];
    int cnt     = csc[b + 1] - base;          // <= PCAP

    // stage + per-target degree histogram
    for (int j = tid; j < cnt; j += 256) {
        int p = ebkt[base_in + j];
        ebl[j] = p;
        atomicAdd(&deg_l[p >> 16], 1);
    }
    __syncthreads();

    // exclusive scan of 128 target degrees
    int v = (tid < 128) ? deg_l[tid] : 0;
    int sv2 = v;
#pragma unroll
    for (int off = 1; off < 64; off <<= 1) {
        int u = __shfl_up(sv2, off, 64);
        if (lane >= off) sv2 += u;
    }
    if (tid == 63) sh.so.wtot = sv2;
    __syncthreads();
    if (tid < 128) {
        int ex = sv2 - v + ((wv == 1) ? sh.so.wtot : 0);
        excl_l[tid] = ex;
        int node = (b << BSH) + tid;
        if (node < N_NODES) rowptr[node] = base + ex;
    }
    __syncthreads();
    for (int j = tid; j < cnt; j += 256) {
        int p  = ebl[j];
        int tl = p >> 16;
        int off = atomicAdd(&cur_l[tl], 1);
        esrc[base + excl_l[tl] + off] = (unsigned short)(p & 0xFFFF);
    }
}

// ============================================================
// K4: pull aggregation, monolithic (R4 lesson: per-head split starves
// occupancy). 16 lanes per node, 8 bf16 ch each; per edge the 16 lanes
// read one contiguous 256B hb row (4 lines, 100% utilized).
// Barrier-free. NT hints: esrc is read-once (nt load), outpb is a pure
// write stream (nt store) -- keeps both out of L2 so hb gather lines
// stay resident.
// ============================================================
__global__ __launch_bounds__(256) void k4_pull(
    const int* __restrict__ rowptr, const unsigned short* __restrict__ esrc,
    const float* __restrict__ s, const float* __restrict__ t,
    const unsigned* __restrict__ smax, const unsigned* __restrict__ tmax,
    const unsigned short* __restrict__ hb, unsigned short* __restrict__ outpb)
{
    int g = blockIdx.x * 256 + threadIdx.x;
    int node = g >> 4;
    int lane = g & 15;
    if (node >= N_NODES) return;
    int head = lane >> 2;                 // 4 lanes per head, 8 ch each
    int beg = rowptr[node];
    int end = rowptr[node + 1];
    float mx = leaky(dec_max(smax[head]) + dec_max(tmax[head]));
    float tv = t[node * HEADS + head];

    float p0 = 0.f, p1 = 0.f, p2 = 0.f, p3 = 0.f;
    float p4 = 0.f, p5 = 0.f, p6 = 0.f, p7 = 0.f, psum = 0.f;
    float q0 = 0.f, q1 = 0.f, q2 = 0.f, q3 = 0.f;
    float q4 = 0.f, q5 = 0.f, q6 = 0.f, q7 = 0.f, qsum = 0.f;
    const unsigned short* hbase = hb + lane * 8;

    for (int j = beg; j < end; j += 8) {
        int lim = end - j;                // >= 1
        int si[8];
#pragma unroll
        for (int u = 0; u < 8; u++) {
            int uu = (u < lim) ? u : (lim - 1);
            si[u] = __builtin_nontemporal_load(&esrc[j + uu]);
        }
        float sv[8];
        us8 hv[8];
#pragma unroll
        for (int u = 0; u < 8; u++) {
            sv[u] = s[si[u] * HEADS + head];
            hv[u] = *(const us8*)(hbase + (size_t)si[u] * HD);
        }
        float al[8];
#pragma unroll
        for (int u = 0; u < 8; u++) {
            float a = __expf(leaky(sv[u] + tv) - mx);
            al[u] = (u < lim) ? a : 0.f;
        }
#pragma unroll
        for (int u = 0; u < 8; u += 2) {
            float a0 = al[u], a1 = al[u + 1];
            p0 = fmaf(a0, bf2f(hv[u][0]), p0);  q0 = fmaf(a1, bf2f(hv[u+1][0]), q0);
            p1 = fmaf(a0, bf2f(hv[u][1]), p1);  q1 = fmaf(a1, bf2f(hv[u+1][1]), q1);
            p2 = fmaf(a0, bf2f(hv[u][2]), p2);  q2 = fmaf(a1, bf2f(hv[u+1][2]), q2);
            p3 = fmaf(a0, bf2f(hv[u][3]), p3);  q3 = fmaf(a1, bf2f(hv[u+1][3]), q3);
            p4 = fmaf(a0, bf2f(hv[u][4]), p4);  q4 = fmaf(a1, bf2f(hv[u+1][4]), q4);
            p5 = fmaf(a0, bf2f(hv[u][5]), p5);  q5 = fmaf(a1, bf2f(hv[u+1][5]), q5);
            p6 = fmaf(a0, bf2f(hv[u][6]), p6);  q6 = fmaf(a1, bf2f(hv[u+1][6]), q6);
            p7 = fmaf(a0, bf2f(hv[u][7]), p7);  q7 = fmaf(a1, bf2f(hv[u+1][7]), q7);
            psum += a0; qsum += a1;
        }
    }

    float w = 1.0f / (psum + qsum + 1e-16f);
    us8 o;
    o[0] = f2bf((p0 + q0) * w); o[1] = f2bf((p1 + q1) * w);
    o[2] = f2bf((p2 + q2) * w); o[3] = f2bf((p3 + q3) * w);
    o[4] = f2bf((p4 + q4) * w); o[5] = f2bf((p5 + q5) * w);
    o[6] = f2bf((p6 + q6) * w); o[7] = f2bf((p7 + q7) * w);
    __builtin_nontemporal_store(o, (us8*)(outpb + (size_t)node * HD + lane * 8));
}

// ============================================================
// K5: BN stats from bf16 outp: per-channel sum & sumsq
// ============================================================
__global__ __launch_bounds__(256) void k5_stats(
    const unsigned short* __restrict__ outpb,
    float* __restrict__ bnsum, float* __restrict__ bnsq)
{
    __shared__ float lsum[HD], lsq[HD];
    int c8  = threadIdx.x & 15;          // channel octet
    int grp = threadIdx.x >> 4;          // row subgroup 0..15
    if (threadIdx.x < HD) { lsum[threadIdx.x] = 0.f; lsq[threadIdx.x] = 0.f; }
    __syncthreads();
    int base = blockIdx.x * 256;
    int end  = min(base + 256, N_NODES);
    float sm[8], sq[8];
#pragma unroll
    for (int i = 0; i < 8; i++) { sm[i] = 0.f; sq[i] = 0.f; }
    for (int r = base + grp; r < end; r += 16) {
        us8 v = *(const us8*)(outpb + (size_t)r * HD + c8 * 8);
#pragma unroll
        for (int i = 0; i < 8; i++) {
            float f = bf2f(v[i]);
            sm[i] += f;
            sq[i] = fmaf(f, f, sq[i]);
        }
    }
#pragma unroll
    for (int i = 0; i < 8; i++) {
        atomicAdd(&lsum[c8 * 8 + i], sm[i]);
        atomicAdd(&lsq[c8 * 8 + i], sq[i]);
    }
    __syncthreads();
    if (threadIdx.x < HD) {
        unsafeAtomicAdd(&bnsum[threadIdx.x], lsum[threadIdx.x]);
        unsafeAtomicAdd(&bnsq[threadIdx.x], lsq[threadIdx.x]);
    }
}

// ============================================================
// K6: BN apply (bf16 in, fp32 out) -> d_out
// ============================================================
__global__ __launch_bounds__(256) void k6_apply(
    const unsigned short* __restrict__ outpb,
    const float* __restrict__ bnsum, const float* __restrict__ bnsq,
    const float* __restrict__ gamma, const float* __restrict__ beta,
    float* __restrict__ out)
{
    int c8  = threadIdx.x & 15;
    int grp = threadIdx.x >> 4;
    int base = blockIdx.x * 256;
    int end  = min(base + 256, N_NODES);
    float inv_n = 1.0f / (float)N_NODES;
    float scale[8], shift[8];
#pragma unroll
    for (int i = 0; i < 8; i++) {
        int c = c8 * 8 + i;
        float mean = bnsum[c] * inv_n;
        float var  = bnsq[c] * inv_n - mean * mean;
        float sc   = gamma[c] * rsqrtf(var + BN_EPS);
        scale[i] = sc;
        shift[i] = beta[c] - mean * sc;
    }
    for (int r = base + grp; r < end; r += 16) {
        us8 v = *(const us8*)(outpb + (size_t)r * HD + c8 * 8);
        float4 o0, o1;
        o0.x = fmaf(bf2f(v[0]), scale[0], shift[0]);
        o0.y = fmaf(bf2f(v[1]), scale[1], shift[1]);
        o0.z = fmaf(bf2f(v[2]), scale[2], shift[2]);
        o0.w = fmaf(bf2f(v[3]), scale[3], shift[3]);
        o1.x = fmaf(bf2f(v[4]), scale[4], shift[4]);
        o1.y = fmaf(bf2f(v[5]), scale[5], shift[5]);
        o1.z = fmaf(bf2f(v[6]), scale[6], shift[6]);
        o1.w = fmaf(bf2f(v[7]), scale[7], shift[7]);
        float* op = out + (size_t)r * HD + c8 * 8;
        ((float4*)op)[0] = o0;
        ((float4*)op)[1] = o1;
    }
}

// ============================================================
extern "C" void kernel_launch(void* const* d_in, const int* in_sizes, int n_in,
                              void* d_out, int out_size, void* d_ws, size_t ws_size,
                              hipStream_t stream)
{
    const float* x     = (const float*)d_in[0];
    const float* W     = (const float*)d_in[1];
    const float* a_src = (const float*)d_in[2];
    const float* a_tgt = (const float*)d_in[3];
    const float* gamma = (const float*)d_in[4];
    const float* beta  = (const float*)d_in[5];
    const int*   eidx  = (const int*)d_in[6];
    const int* src = eidx;
    const int* tgt = eidx + E_EDGES;
    float* out = (float*)d_out;

    // workspace layout
    unsigned short* hb    = (unsigned short*)d_ws;          // 6.4M ushort
    float*          s     = (float*)d_ws + 3200000;         // 200K float
    float*          t     = s + (size_t)N_NODES * HEADS;    // 200K float
    unsigned short* outpb = (unsigned short*)(t + (size_t)N_NODES * HEADS); // 6.4M us
    int*            ebkt  = (int*)outpb;                    // NB*PCAP=1.0M int (aliases outpb)
    unsigned short* esrc  = outpb + 6400000;                // 800K ushort
    int*            rowptr= (int*)(esrc + E_EDGES);         // 50,001 int
    // ---- zero-init region (single memset) ----
    int*      bcur  = rowptr + N_NODES + 1;                 // 392
    unsigned* smax  = (unsigned*)(bcur + 392);              // 4
    unsigned* tmax  = smax + 4;                             // 4
    float*    bnsum = (float*)(tmax + 4);                   // 128
    float*    bnsq  = bnsum + HD;                           // 128
    size_t zero_bytes = (392 + 8 + HD + HD) * 4;
    hipMemsetAsync(bcur, 0, zero_bytes, stream);

    // F1: GEMM || edge bucketing (independent inputs, forced overlap)
    f1_gemm_fill<<<K1B + FB, 256, 0, stream>>>(x, W, a_src, a_tgt,
                                               src, tgt, bcur, ebkt,
                                               hb, s, t);
    // F2: bucket fine-sort || per-head node max
    f2_sort_max<<<NB + K2_BLOCKS, 256, 0, stream>>>(bcur, ebkt, rowptr, esrc,
                                                    s, t, smax, tmax);
    // pull aggregation (no atomics, no barriers), bf16 h gather, bf16 out
    long long k4_threads = (long long)N_NODES * 16;
    k4_pull<<<(unsigned)((k4_threads + 255) / 256), 256, 0, stream>>>(
        rowptr, esrc, s, t, smax, tmax, hb, outpb);
    // BN
    k5_stats<<<(N_NODES + 255) / 256, 256, 0, stream>>>(outpb, bnsum, bnsq);
    k6_apply<<<(N_NODES + 255) / 256, 256, 0, stream>>>(outpb, bnsum, bnsq,
                                                        gamma, beta, out);
}